// Round 1
// 581.790 us; speedup vs baseline: 1.0182x; 1.0182x over previous
//
#include <hip/hip_runtime.h>
#include <math.h>

#define EPSF 1e-16f
constexpr int B = 64, N = 16384, M = 64;
constexpr int ROWS_PER_BLOCK = 64;   // 256 threads: 4 waves x 4 rows/iter x 4 iters

typedef float vf4 __attribute__((ext_vector_type(4)));

__device__ __forceinline__ float red16(float v) {
    v += __shfl_xor(v, 1);
    v += __shfl_xor(v, 2);
    v += __shfl_xor(v, 4);
    v += __shfl_xor(v, 8);
    return v;
}
__device__ __forceinline__ float red64(float v) {
    v += __shfl_xor(v, 1);
    v += __shfl_xor(v, 2);
    v += __shfl_xor(v, 4);
    v += __shfl_xor(v, 8);
    v += __shfl_xor(v, 16);
    v += __shfl_xor(v, 32);
    return v;
}

// K1: e[b,n] = exp(beta * cos_sim(mem[b,n,:], key[b,:])); sum_e[b] += partials
// Loads of mem are CACHING on purpose: they populate L3 so K3 (reversed) can hit.
__global__ __launch_bounds__(256) void k1_sim(const float* __restrict__ mem,
                                              const float* __restrict__ key,
                                              const float* __restrict__ beta,
                                              float* __restrict__ e_out,
                                              float* __restrict__ sum_e) {
    const int b    = blockIdx.y;
    const int tid  = threadIdx.x;
    const int wave = tid >> 6;
    const int lane = tid & 63;
    const int sub  = lane >> 4;   // row within wave's 4-row group
    const int q    = lane & 15;   // float4 column index

    const float4 k4 = ((const float4*)(key + b * M))[q];
    float kk = k4.x * k4.x + k4.y * k4.y + k4.z * k4.z + k4.w * k4.w;
    kk = red16(kk);
    const float knorm = sqrtf(kk);
    const float bet = beta[b];

    float local = 0.f;
    const int row0 = blockIdx.x * ROWS_PER_BLOCK;
#pragma unroll
    for (int it = 0; it < 4; ++it) {
        const int row = row0 + it * 16 + wave * 4 + sub;
        const float4 m4 = ((const float4*)(mem + ((size_t)b * N + row) * M))[q];
        float d  = m4.x * k4.x + m4.y * k4.y + m4.z * k4.z + m4.w * k4.w;
        float nn = m4.x * m4.x + m4.y * m4.y + m4.z * m4.z + m4.w * m4.w;
        d  = red16(d);
        nn = red16(nn);
        const float sim = d / fmaxf(sqrtf(nn) * knorm, EPSF);
        const float e = expf(bet * sim);
        if (q == 0) {
            e_out[(size_t)b * N + row] = e;
            local += e;
        }
    }
    local = red64(local);   // only q==0 lanes contributed, others 0
    __shared__ float lds[4];
    if (lane == 0) lds[wave] = local;
    __syncthreads();
    if (tid == 0) atomicAdd(&sum_e[b], lds[0] + lds[1] + lds[2] + lds[3]);
}

// K2: wpow[b,n] = (s0*wg[n-1] + s1*wg[n] + s2*wg[n+1]) ^ sharpen ; sum_pow[b] += partials
//     wg[n] = g*e[n]/sum_e + (1-g)*prev_w[n]   (circular indexing, N power of 2)
__global__ __launch_bounds__(256) void k2_shift(const float* __restrict__ e_in,
                                                const float* __restrict__ prev_w,
                                                const float* __restrict__ gate,
                                                const float* __restrict__ shiftw,
                                                const float* __restrict__ sharpen,
                                                const float* __restrict__ sum_e,
                                                float* __restrict__ wpow,
                                                float* __restrict__ sum_pow) {
    const int idx = blockIdx.x * 256 + threadIdx.x;   // [0, B*N) ; block spans single b
    const int b = idx >> 14;
    const int n = idx & (N - 1);
    const float inv = 1.f / sum_e[b];
    const float g   = gate[b];
    const float s0 = shiftw[b * 3 + 0];
    const float s1 = shiftw[b * 3 + 1];
    const float s2 = shiftw[b * 3 + 2];
    const float sh = sharpen[b];
    const size_t base = (size_t)b * N;
    const int nm = (n - 1) & (N - 1);
    const int np = (n + 1) & (N - 1);
    const float gi = g * inv, om = 1.f - g;
    const float wgm = gi * e_in[base + nm] + om * prev_w[base + nm];
    const float wg0 = gi * e_in[base + n ] + om * prev_w[base + n ];
    const float wgp = gi * e_in[base + np] + om * prev_w[base + np];
    const float wsv = s0 * wgm + s1 * wg0 + s2 * wgp;
    const float wp = powf(wsv, sh);
    wpow[idx] = wp;

    float v = red64(wp);
    __shared__ float lds[4];
    if ((threadIdx.x & 63) == 0) lds[threadIdx.x >> 6] = v;
    __syncthreads();
    if (threadIdx.x == 0) atomicAdd(&sum_pow[b], lds[0] + lds[1] + lds[2] + lds[3]);
}

// K3: w = wpow/(sum_pow+eps); new_mem = mem*(1 + w*(add-erase)); read += w*mem (atomics)
// REVERSED traversal: earliest blocks touch the mem lines K1 streamed last (L3-hot).
// mem loads + new_mem stores are non-temporal: mem is dead after this read, and the
// new_mem write stream must not evict the residual mem lines from L3.
__global__ __launch_bounds__(256) void k3_update(const float* __restrict__ mem,
                                                 const float* __restrict__ erase,
                                                 const float* __restrict__ addv,
                                                 const float* __restrict__ wpow,
                                                 const float* __restrict__ sum_pow,
                                                 float* __restrict__ read_out,
                                                 float* __restrict__ new_mem,
                                                 float* __restrict__ w_out) {
    const int b    = (B - 1) - blockIdx.y;
    const int tid  = threadIdx.x;
    const int wave = tid >> 6;
    const int lane = tid & 63;
    const int sub  = lane >> 4;
    const int q    = lane & 15;

    const float inv = 1.f / (sum_pow[b] + EPSF);
    const float4 e4 = ((const float4*)(erase + b * M))[q];
    const float4 a4 = ((const float4*)(addv  + b * M))[q];
    const float4 d4 = make_float4(a4.x - e4.x, a4.y - e4.y, a4.z - e4.z, a4.w - e4.w);

    float4 racc = make_float4(0.f, 0.f, 0.f, 0.f);
    const int row0 = N - ROWS_PER_BLOCK - blockIdx.x * ROWS_PER_BLOCK;
#pragma unroll
    for (int it = 3; it >= 0; --it) {
        const int row = row0 + it * 16 + wave * 4 + sub;
        const size_t roff = ((size_t)b * N + row) * M;
        const float w = wpow[(size_t)b * N + row] * inv;
        const vf4 m4 = __builtin_nontemporal_load((const vf4*)(mem + roff) + q);
        vf4 nm4;
        nm4.x = m4.x * (1.f + w * d4.x);
        nm4.y = m4.y * (1.f + w * d4.y);
        nm4.z = m4.z * (1.f + w * d4.z);
        nm4.w = m4.w * (1.f + w * d4.w);
        __builtin_nontemporal_store(nm4, (vf4*)(new_mem + roff) + q);
        racc.x += w * m4.x;
        racc.y += w * m4.y;
        racc.z += w * m4.z;
        racc.w += w * m4.w;
        if (q == 0) w_out[(size_t)b * N + row] = w;
    }
    // combine the 4 row-groups within the wave (lanes differing in bits 4,5)
#pragma unroll
    for (int m = 16; m <= 32; m <<= 1) {
        racc.x += __shfl_xor(racc.x, m);
        racc.y += __shfl_xor(racc.y, m);
        racc.z += __shfl_xor(racc.z, m);
        racc.w += __shfl_xor(racc.w, m);
    }
    __shared__ float lds[4][64];
    if (sub == 0) {
        lds[wave][q * 4 + 0] = racc.x;
        lds[wave][q * 4 + 1] = racc.y;
        lds[wave][q * 4 + 2] = racc.z;
        lds[wave][q * 4 + 3] = racc.w;
    }
    __syncthreads();
    if (wave == 0) {
        const float s = lds[0][lane] + lds[1][lane] + lds[2][lane] + lds[3][lane];
        atomicAdd(&read_out[b * M + lane], s);
    }
}

extern "C" void kernel_launch(void* const* d_in, const int* in_sizes, int n_in,
                              void* d_out, int out_size, void* d_ws, size_t ws_size,
                              hipStream_t stream) {
    const float* mem     = (const float*)d_in[0];
    const float* key     = (const float*)d_in[1];
    const float* beta    = (const float*)d_in[2];
    const float* gate    = (const float*)d_in[3];
    const float* shiftw  = (const float*)d_in[4];
    const float* sharpen = (const float*)d_in[5];
    const float* prev_w  = (const float*)d_in[6];
    const float* erase   = (const float*)d_in[7];
    const float* addv    = (const float*)d_in[8];

    float* out      = (float*)d_out;
    float* read_out = out;                          // B*M
    float* new_mem  = out + B * M;                  // B*N*M
    float* w_out    = out + B * M + (size_t)B * N * M;  // B*N

    float* ws      = (float*)d_ws;
    float* sum_e   = ws;          // B floats
    float* sum_pow = ws + 64;     // B floats
    float* wpow    = ws + 128;    // B*N floats

    // e scratch lives in the w output region (overwritten with final w in K3)
    float* e_buf = w_out;

    hipMemsetAsync(sum_e, 0, 2 * 64 * sizeof(float), stream);
    hipMemsetAsync(read_out, 0, B * M * sizeof(float), stream);

    dim3 grid1(N / ROWS_PER_BLOCK, B);   // (256, 64)
    k1_sim<<<grid1, 256, 0, stream>>>(mem, key, beta, e_buf, sum_e);
    k2_shift<<<(B * N) / 256, 256, 0, stream>>>(e_buf, prev_w, gate, shiftw, sharpen,
                                                sum_e, wpow, sum_pow);
    k3_update<<<grid1, 256, 0, stream>>>(mem, erase, addv, wpow, sum_pow,
                                         read_out, new_mem, w_out);
}